// Round 10
// baseline (679.120 us; speedup 1.0000x reference)
//
#include <hip/hip_runtime.h>

// ---------------------------------------------------------------------------
// HeteroGATv2Encoder on MI355X (gfx950).
// fp32 in / fp32 out. R10: merged-CSR GAT — one wave per NODE walks a single
// merged edge row (et0|et1|et2 segments, entry=src*3+et so gather addr is
// entry*1024 (L01) / entry*512 (L2)); one branchless depth-3 prefetch stream
// across segment boundaries; per-segment softmax fold; block=4 independent
// nodes, NO syncthreads/LDS. GEMMs unchanged from R7 (gemm256 for N=3072,
// 128^2 for proj/N=1536). Scalar edge math (R9 packed-f32 regressed: VGPR 44
// -> occ 45%).
// ---------------------------------------------------------------------------

#define NN 20000      // nodes
#define NE 100000     // edges per relation
#define DH 512        // hidden width (8 heads x 64)
#define DOUT 256

typedef __attribute__((ext_vector_type(8))) short short8;
typedef __attribute__((ext_vector_type(4))) float f32x4;

__device__ __forceinline__ float b2f(unsigned short s) {
    union { unsigned u; float f; } v; v.u = ((unsigned)s) << 16; return v.f;
}
__device__ __forceinline__ unsigned short f2b(float f) {
    unsigned u = __float_as_uint(f);
    u += 0x7FFFu + ((u >> 16) & 1u);   // RNE
    return (unsigned short)(u >> 16);
}
__device__ __forceinline__ void load_lds16(const unsigned short* g, unsigned short* l) {
    __builtin_amdgcn_global_load_lds(
        (const __attribute__((address_space(1))) unsigned int*)g,
        (__attribute__((address_space(3))) unsigned int*)l, 16, 0, 0);
}

// ---------------------------------------------------------------------------
__global__ void cvt_f2b_k(const float* __restrict__ in,
                          unsigned short* __restrict__ out, int n) {
    int i0 = (blockIdx.x * blockDim.x + threadIdx.x) * 8;
    if (i0 >= n) return;
    #pragma unroll
    for (int j = 0; j < 8; j++) out[i0 + j] = f2b(in[i0 + j]);
}

// ---------------------------------------------------------------------------
// Merged transpose+cast: 19 weight matrices in one launch.
// ---------------------------------------------------------------------------
struct TSeg { const float* in; unsigned short* out; int C; };
struct TTable { TSeg s[19]; };

__global__ void transpose_all_k(TTable t) {
    __shared__ float tile[32][33];
    TSeg d = t.s[blockIdx.y];
    int tiles_x = d.C >> 5;
    int nt = tiles_x << 4;               // tiles_x * 16
    if ((int)blockIdx.x >= nt) return;
    int bx = blockIdx.x % tiles_x, by = blockIdx.x / tiles_x;
    int c0 = bx * 32, r0 = by * 32;
    int tx = threadIdx.x & 31, ty = threadIdx.x >> 5;
    #pragma unroll
    for (int i = ty; i < 32; i += 8)
        tile[i][tx] = d.in[(size_t)(r0 + i) * d.C + c0 + tx];
    __syncthreads();
    #pragma unroll
    for (int i = ty; i < 32; i += 8)
        d.out[(size_t)(c0 + i) * 512 + r0 + tx] = f2b(tile[tx][i]);
}

// ---------------------------------------------------------------------------
// CSR build (merged over the 3 relations). Merged row per node:
// [et0 edges | et1 edges | et2 edges], entry = src*3 + et.
// ---------------------------------------------------------------------------
__global__ void count_all_k(const int* __restrict__ ei, int* __restrict__ counts) {
    int i = blockIdx.x * blockDim.x + threadIdx.x;
    if (i >= 3 * NE) return;
    int et = i / NE, idx = i - et * NE;
    int d = ei[(size_t)et * 2 * NE + NE + idx];
    atomicAdd(&counts[et * (NN + 1) + d], 1);
}

__global__ __launch_bounds__(1024)
void scan_par_k(const int* __restrict__ counts, int* __restrict__ offs, int n) {
    __shared__ int part[1024];
    const int* c = counts + (size_t)blockIdx.x * (n + 1);
    int* o = offs + (size_t)blockIdx.x * (n + 1);
    int tid = threadIdx.x;
    int per = (n + 1023) / 1024;
    int base = tid * per;
    int lim = min(base + per, n);
    int sum = 0;
    for (int i = base; i < lim; i++) sum += c[i];
    part[tid] = sum;
    __syncthreads();
    #pragma unroll
    for (int off = 1; off < 1024; off <<= 1) {
        int v = (tid >= off) ? part[tid - off] : 0;
        __syncthreads();
        part[tid] += v;
        __syncthreads();
    }
    int run = part[tid] - sum;
    for (int i = base; i < lim; i++) { o[i] = run; run += c[i]; }
    if (tid == 1023) o[n] = part[1023];
}

// cursor3[et*NN+n] = start of (n, et) segment in the merged array.
__global__ void cursor_init_k(const int* __restrict__ offs3,
                              int* __restrict__ cur3) {
    int n = blockIdx.x * blockDim.x + threadIdx.x;
    if (n >= NN) return;
    int o0a = offs3[n],                o0b = offs3[n + 1];
    int o1a = offs3[(NN + 1) + n],     o1b = offs3[(NN + 1) + n + 1];
    int o2a = offs3[2 * (NN + 1) + n];
    int S = o0a + o1a + o2a;
    cur3[n]          = S;
    cur3[NN + n]     = S + (o0b - o0a);
    cur3[2 * NN + n] = S + (o0b - o0a) + (o1b - o1a);
}

__global__ void scatter_all_k(const int* __restrict__ ei, int* __restrict__ cursor,
                              int* __restrict__ srcm) {
    int i = blockIdx.x * blockDim.x + threadIdx.x;
    if (i >= 3 * NE) return;
    int et = i / NE, idx = i - et * NE;
    int s = ei[(size_t)et * 2 * NE + idx];
    int d = ei[(size_t)et * 2 * NE + NE + idx];
    int p = atomicAdd(&cursor[et * NN + d], 1);
    srcm[p] = s * 3 + et;
}

// ---------------------------------------------------------------------------
// 128x128 4-wave GEMM — proj (small grid) and N=1536 (tail fill).
// ---------------------------------------------------------------------------
template<int ACT, int SEGL2>
__global__ __launch_bounds__(256)
void gemm_k(const unsigned short* __restrict__ A,
            const unsigned short* __restrict__ Bt,
            const float* __restrict__ lb,
            const float* __restrict__ rb,
            unsigned short* __restrict__ Cb,
            int M, int N, int K, int MT, int NT, int STRIPE) {
    __shared__ __align__(16) unsigned short smem[17408];   // 34.8 KB
    unsigned short* As = smem;           // 128*64
    unsigned short* Bs = smem + 8192;    // 128*64
    int bid = blockIdx.x;
    int xcd = bid & 7, r = bid >> 3;
    int mtile = xcd * STRIPE + r / NT;
    int ntile = r % NT;
    if (mtile >= MT) return;
    int bm0 = mtile * 128, bn0 = ntile * 128;

    int tid = threadIdx.x;
    int lane = tid & 63, wave = tid >> 6;
    int quad = lane >> 4, l16 = lane & 15;
    int rw = (wave >> 1) * 64, cw = (wave & 1) * 64;
    int rxor = l16 & 7;

    f32x4 acc[4][4];
    #pragma unroll
    for (int mi = 0; mi < 4; mi++)
        #pragma unroll
        for (int ni = 0; ni < 4; ni++) acc[mi][ni] = (f32x4){0.f, 0.f, 0.f, 0.f};

    for (int k0 = 0; k0 < K; k0 += 64) {
        #pragma unroll
        for (int i = 0; i < 4; i++) {
            int f = i * 256 + tid;
            int row = f >> 3, s = f & 7;
            int cg = s ^ (row & 7);
            load_lds16(A + (size_t)(bm0 + row) * K + k0 + cg * 8, As + f * 8);
        }
        #pragma unroll
        for (int i = 0; i < 4; i++) {
            int f = i * 256 + tid;
            int col = f >> 3, s = f & 7;
            int cg = s ^ (col & 7);
            load_lds16(Bt + (size_t)(bn0 + col) * K + k0 + cg * 8, Bs + f * 8);
        }
        __syncthreads();
        #pragma unroll
        for (int ki = 0; ki < 64; ki += 32) {
            int kch = quad + (ki >> 3);
            int slot = kch ^ rxor;
            short8 af[4], bf[4];
            #pragma unroll
            for (int mi = 0; mi < 4; mi++)
                af[mi] = *(const short8*)(As + (rw + mi * 16 + l16) * 64 + slot * 8);
            #pragma unroll
            for (int ni = 0; ni < 4; ni++)
                bf[ni] = *(const short8*)(Bs + (cw + ni * 16 + l16) * 64 + slot * 8);
            #pragma unroll
            for (int mi = 0; mi < 4; mi++)
                #pragma unroll
                for (int ni = 0; ni < 4; ni++)
                    acc[mi][ni] = __builtin_amdgcn_mfma_f32_16x16x32_bf16(
                        af[mi], bf[ni], acc[mi][ni], 0, 0, 0);
        }
        __syncthreads();
    }

    #pragma unroll
    for (int ni = 0; ni < 4; ni++) {
        int col = cw + ni * 16 + l16;
        int seg = col >> (SEGL2 + 1);
        int lr = (col >> SEGL2) & 1;
        int cc2 = col & ((1 << SEGL2) - 1);
        float bv = (lr ? rb : lb)[(seg << SEGL2) + cc2];
        #pragma unroll
        for (int mi = 0; mi < 4; mi++) {
            int row = rw + mi * 16 + quad * 4;
            #pragma unroll
            for (int i = 0; i < 4; i++) {
                float v = acc[mi][ni][i] + bv;
                if (ACT == 1) v = v > 0.f ? v : expm1f(v);
                smem[(row + i) * 136 + col] = f2b(v);
            }
        }
    }
    __syncthreads();
    #pragma unroll
    for (int it = 0; it < 8; it++) {
        int chunk = it * 256 + tid;
        int row = chunk >> 4, cc = chunk & 15;
        int grow = bm0 + row;
        if (grow < M) {
            uint4 d = *(const uint4*)(smem + row * 136 + cc * 8);
            *(uint4*)(Cb + (size_t)grow * N + bn0 + cc * 8) = d;
        }
    }
}

// ---------------------------------------------------------------------------
// 256x256 8-wave free-running GEMM (one barrier per K-tile, front-loaded
// staging, register-pipelined A-fragments). Used for the N=3072 GEMMs.
// ---------------------------------------------------------------------------
#define MMAC(AF, P)                                                         \
    __builtin_amdgcn_s_setprio(1);                                          \
    _Pragma("unroll")                                                       \
    for (int mi = 0; mi < 2; mi++)                                          \
        _Pragma("unroll")                                                   \
        for (int nn = 0; nn < 4; nn++)                                      \
            _Pragma("unroll")                                               \
            for (int s2 = 0; s2 < 2; s2++)                                  \
                acc[2 * (P) + mi][nn] = __builtin_amdgcn_mfma_f32_16x16x32_bf16( \
                    AF[mi][s2], bfr[nn][s2], acc[2 * (P) + mi][nn], 0, 0, 0); \
    __builtin_amdgcn_s_setprio(0);

template<int ACT, int SEGL2>
__global__ __launch_bounds__(512, 2)
void gemm256_k(const unsigned short* __restrict__ A,
               const unsigned short* __restrict__ Bt,
               const float* __restrict__ lb,
               const float* __restrict__ rb,
               unsigned short* __restrict__ Cb,
               int M, int N, int K, int MT, int NT) {
    // [2 bufs][A 16384 | B 16384] shorts = 65536 shorts = 128 KB
    __shared__ __align__(16) unsigned short smem[65536];

    int bid = blockIdx.x;
    int nwg = MT * NT;
    int q = nwg >> 3, r = nwg & 7;
    int xcd = bid & 7;
    int wg = (xcd < r ? xcd * (q + 1) : r * (q + 1) + (xcd - r) * q) + (bid >> 3);
    int mtile = wg / NT, ntile = wg % NT;
    int bm0 = mtile * 256, bn0 = ntile * 256;

    int tid = threadIdx.x;
    int lane = tid & 63, wid = tid >> 6;       // 8 waves
    int wr = wid >> 2, wc = wid & 3;           // 2 x 4
    int quad = lane >> 4, l16 = lane & 15;
    int rbase = wr * 128, cbase = wc * 64;
    int rxor = l16 & 7;

    f32x4 acc[8][4];
    #pragma unroll
    for (int m = 0; m < 8; m++)
        #pragma unroll
        for (int n = 0; n < 4; n++) acc[m][n] = (f32x4){0.f, 0.f, 0.f, 0.f};

    const int NKT = K >> 6;                    // 8 for K=512

    auto stage2 = [&](int grp, int kt1) {      // 1 A-load + 1 B-load
        unsigned short* Asw = smem + (kt1 & 1) * 32768;
        unsigned short* Bsw = Asw + 16384;
        int kk = kt1 << 6;
        int f = grp * 512 + tid;
        int row = f >> 3, s = f & 7;
        int cg = s ^ (row & 7);
        load_lds16(A + (size_t)(bm0 + row) * K + kk + cg * 8, Asw + f * 8);
        load_lds16(Bt + (size_t)(bn0 + row) * K + kk + cg * 8, Bsw + f * 8);
    };
    auto readA = [&](short8 (&dst)[2][2], const unsigned short* Asr, int p) {
        #pragma unroll
        for (int mi = 0; mi < 2; mi++)
            #pragma unroll
            for (int s2 = 0; s2 < 2; s2++)
                dst[mi][s2] = *(const short8*)(Asr +
                    (rbase + (2 * p + mi) * 16 + l16) * 64 +
                    ((quad + s2 * 4) ^ rxor) * 8);
    };

    stage2(0, 0); stage2(1, 0); stage2(2, 0); stage2(3, 0);
    __syncthreads();                            // drains vmcnt(0) + barrier

    short8 afA[2][2], afB[2][2], bfr[4][2];
    {
        const unsigned short* A0 = smem;
        const unsigned short* B0 = smem + 16384;
        #pragma unroll
        for (int n = 0; n < 4; n++)
            #pragma unroll
            for (int s2 = 0; s2 < 2; s2++)
                bfr[n][s2] = *(const short8*)(B0 +
                    (cbase + n * 16 + l16) * 64 + ((quad + s2 * 4) ^ rxor) * 8);
        readA(afA, A0, 0);
    }

    for (int kt = 0; kt < NKT; kt++) {
        const unsigned short* Asr = smem + (kt & 1) * 32768;
        bool st = (kt + 1 < NKT);

        if (st) { stage2(0, kt + 1); stage2(1, kt + 1); }
        __builtin_amdgcn_sched_barrier(0);
        readA(afB, Asr, 1);
        MMAC(afA, 0)
        if (st) { stage2(2, kt + 1); stage2(3, kt + 1); }
        __builtin_amdgcn_sched_barrier(0);
        readA(afA, Asr, 2);
        MMAC(afB, 1)
        readA(afB, Asr, 3);
        MMAC(afA, 2)
        MMAC(afB, 3)

        __syncthreads();   // drains vmcnt(0)+lgkmcnt(0); staging ~2 phases old

        if (st) {
            const unsigned short* An = smem + ((kt + 1) & 1) * 32768;
            const unsigned short* Bn = An + 16384;
            #pragma unroll
            for (int n = 0; n < 4; n++)
                #pragma unroll
                for (int s2 = 0; s2 < 2; s2++)
                    bfr[n][s2] = *(const short8*)(Bn +
                        (cbase + n * 16 + l16) * 64 + ((quad + s2 * 4) ^ rxor) * 8);
            readA(afA, An, 0);
        }
    }

    #pragma unroll
    for (int h = 0; h < 2; h++) {
        __syncthreads();
        if (wr == h) {
            #pragma unroll
            for (int n = 0; n < 4; n++) {
                int col = cbase + n * 16 + l16;
                int gcol = bn0 + col;
                int seg = gcol >> (SEGL2 + 1);
                int lr = (gcol >> SEGL2) & 1;
                int cc2 = gcol & ((1 << SEGL2) - 1);
                float bv = (lr ? rb : lb)[(seg << SEGL2) + cc2];
                #pragma unroll
                for (int m = 0; m < 8; m++) {
                    int lrow = m * 16 + quad * 4;
                    #pragma unroll
                    for (int i = 0; i < 4; i++) {
                        float v = acc[m][n][i] + bv;
                        if (ACT == 1) v = v > 0.f ? v : expm1f(v);
                        smem[(lrow + i) * 264 + col] = f2b(v);
                    }
                }
            }
        }
        __syncthreads();
        #pragma unroll
        for (int it = 0; it < 8; it++) {
            int chunk = it * 512 + tid;
            int row = chunk >> 5, cc = chunk & 31;
            int grow = bm0 + h * 128 + row;
            if (grow < M) {
                uint4 d = *(const uint4*)(smem + row * 264 + cc * 8);
                *(uint4*)(Cb + (size_t)grow * N + bn0 + cc * 8) = d;
            }
        }
    }
}

// ---------------------------------------------------------------------------
// Fused layer 0/1: ONE WAVE PER NODE (block 256 = 4 independent nodes, no
// LDS/sync). Merged edge row walked with one branchless depth-3 prefetch
// stream; per-et segment: load xr/att, accumulate z/acc, fold tot+=acc/z.
// Gather addr = entry*1024 (entry = src*3+et). Finalize (bias+ELU+residual+
// LN over 512 via 6-shuffle reduce) per wave.
// C layout [NN][3072] = et: XL(512)|XR(512).
// ---------------------------------------------------------------------------
__global__ __launch_bounds__(256)
void gat_fused01_k(const unsigned short* __restrict__ C,
                   const int* __restrict__ offs3,
                   const int* __restrict__ srcm,
                   const float* __restrict__ att,     // [3][512]
                   const float* __restrict__ bias3,   // [3][512]
                   unsigned short* __restrict__ hb,   // in/out
                   const float* __restrict__ gamma,
                   const float* __restrict__ beta,
                   int n_nodes) {
    int tid = threadIdx.x;
    int lane = tid & 63;
    int n = blockIdx.x * 4 + (tid >> 6);
    if (n >= n_nodes) return;
    int cl = lane * 8;
    const unsigned short* Cl = C + cl;

    // merged row geometry from the 3 per-et offset arrays
    int o0a = offs3[n],                o0b = offs3[n + 1];
    int o1a = offs3[(NN + 1) + n],     o1b = offs3[(NN + 1) + n + 1];
    int o2a = offs3[2 * (NN + 1) + n], o2b = offs3[2 * (NN + 1) + n + 1];
    int S = o0a + o1a + o2a;
    int b1 = S + (o0b - o0a);
    int b2 = b1 + (o1b - o1a);
    int E = b2 + (o2b - o2a);

    float tot[8];
    #pragma unroll
    for (int j = 0; j < 8; j++) tot[j] = 0.f;

    if (S < E) {
        int last = E - 1;
        auto G = [&](int i) {
            return *(const uint4*)(Cl + (size_t)(unsigned)srcm[i] * 1024);
        };
        uint4 p0 = G(S);
        uint4 p1 = G(min(S + 1, last));
        uint4 p2 = G(min(S + 2, last));
        int e = S;
        float xr[8], at[8];

        #pragma unroll
        for (int et = 0; et < 3; et++) {
            int segend = (et == 0) ? b1 : ((et == 1) ? b2 : E);
            if (e < segend) {
                {
                    short8 t = *(const short8*)(C + (size_t)(n * 3 + et) * 1024 + 512 + cl);
                    #pragma unroll
                    for (int j = 0; j < 8; j++) xr[j] = b2f((unsigned short)t[j]);
                    #pragma unroll
                    for (int j = 0; j < 8; j++) at[j] = att[et * 512 + cl + j];
                }
                float z = 0.f, acc[8];
                #pragma unroll
                for (int j = 0; j < 8; j++) acc[j] = 0.f;
                for (; e < segend; e++) {
                    uint4 cur = p0; p0 = p1; p1 = p2; p2 = G(min(e + 3, last));
                    float xl[8];
                    xl[0] = __uint_as_float(cur.x << 16);
                    xl[1] = __uint_as_float(cur.x & 0xffff0000u);
                    xl[2] = __uint_as_float(cur.y << 16);
                    xl[3] = __uint_as_float(cur.y & 0xffff0000u);
                    xl[4] = __uint_as_float(cur.z << 16);
                    xl[5] = __uint_as_float(cur.z & 0xffff0000u);
                    xl[6] = __uint_as_float(cur.w << 16);
                    xl[7] = __uint_as_float(cur.w & 0xffff0000u);
                    float p = 0.f;
                    #pragma unroll
                    for (int j = 0; j < 8; j++) {
                        float v = xl[j] + xr[j];
                        v = fmaxf(v, 0.2f * v);      // leaky_relu 0.2
                        p = fmaf(v, at[j], p);
                    }
                    p += __shfl_xor(p, 1, 64);       // head = 8-lane group
                    p += __shfl_xor(p, 2, 64);
                    p += __shfl_xor(p, 4, 64);
                    float wgt = __expf(p);           // no-max: |p| small, safe
                    z += wgt;
                    #pragma unroll
                    for (int j = 0; j < 8; j++) acc[j] = fmaf(wgt, xl[j], acc[j]);
                }
                float inv = 1.f / z;
                #pragma unroll
                for (int j = 0; j < 8; j++) tot[j] = fmaf(acc[j], inv, tot[j]);
            }
        }
    }

    // finalize: bias + ELU + residual + LN (wave holds all 512 ch)
    unsigned short* hrow = hb + (size_t)n * DH + cl;
    short8 rt = *(const short8*)hrow;
    float v[8];
    float s1 = 0.f;
    #pragma unroll
    for (int j = 0; j < 8; j++) {
        int c = cl + j;
        float x = tot[j] + bias3[c] + bias3[512 + c] + bias3[1024 + c];
        x = x > 0.f ? x : expm1f(x);
        x += b2f((unsigned short)rt[j]);
        v[j] = x;
        s1 += x;
    }
    #pragma unroll
    for (int off = 1; off < 64; off <<= 1) s1 += __shfl_xor(s1, off, 64);
    float mean = s1 * (1.f / DH);
    float s2 = 0.f;
    #pragma unroll
    for (int j = 0; j < 8; j++) { float d = v[j] - mean; s2 += d * d; }
    #pragma unroll
    for (int off = 1; off < 64; off <<= 1) s2 += __shfl_xor(s2, off, 64);
    float rstd = rsqrtf(s2 * (1.f / DH) + 1e-5f);
    short8 ov;
    #pragma unroll
    for (int j = 0; j < 8; j++) {
        int c = cl + j;
        ov[j] = (short)f2b((v[j] - mean) * rstd * gamma[c] + beta[c]);
    }
    *(short8*)hrow = ov;
}

// ---------------------------------------------------------------------------
// Fused layer 2: one wave per node, merged stream (addr = entry*512),
// 4 ch/lane, single head (64-lane reduce), per-segment fold, LN -> f32 out.
// C layout [NN][1536] = et: XL(256)|XR(256).
// ---------------------------------------------------------------------------
__global__ __launch_bounds__(256)
void gat_fused2_k(const unsigned short* __restrict__ C,
                  const int* __restrict__ offs3,
                  const int* __restrict__ srcm,
                  const float* __restrict__ att,     // [3][256]
                  const float* __restrict__ bias3,   // [3][256]
                  const float* __restrict__ gamma,
                  const float* __restrict__ beta,
                  float* __restrict__ out, int n_nodes) {
    int tid = threadIdx.x;
    int lane = tid & 63;
    int n = blockIdx.x * 4 + (tid >> 6);
    if (n >= n_nodes) return;
    int cl = lane * 4;
    const unsigned short* Cl = C + cl;

    int o0a = offs3[n],                o0b = offs3[n + 1];
    int o1a = offs3[(NN + 1) + n],     o1b = offs3[(NN + 1) + n + 1];
    int o2a = offs3[2 * (NN + 1) + n], o2b = offs3[2 * (NN + 1) + n + 1];
    int S = o0a + o1a + o2a;
    int b1 = S + (o0b - o0a);
    int b2 = b1 + (o1b - o1a);
    int E = b2 + (o2b - o2a);

    float tot[4] = {0.f, 0.f, 0.f, 0.f};

    if (S < E) {
        int last = E - 1;
        auto G = [&](int i) {
            return *(const uint2*)(Cl + (size_t)(unsigned)srcm[i] * 512);
        };
        uint2 p0 = G(S);
        uint2 p1 = G(min(S + 1, last));
        uint2 p2 = G(min(S + 2, last));
        int e = S;
        float xr[4], at[4];

        #pragma unroll
        for (int et = 0; et < 3; et++) {
            int segend = (et == 0) ? b1 : ((et == 1) ? b2 : E);
            if (e < segend) {
                {
                    const unsigned short* xrp = C + (size_t)(n * 3 + et) * 512 + 256 + cl;
                    #pragma unroll
                    for (int j = 0; j < 4; j++) xr[j] = b2f(xrp[j]);
                    #pragma unroll
                    for (int j = 0; j < 4; j++) at[j] = att[et * 256 + cl + j];
                }
                float z = 0.f, acc[4];
                #pragma unroll
                for (int j = 0; j < 4; j++) acc[j] = 0.f;
                for (; e < segend; e++) {
                    uint2 cur = p0; p0 = p1; p1 = p2; p2 = G(min(e + 3, last));
                    float xl[4];
                    xl[0] = __uint_as_float(cur.x << 16);
                    xl[1] = __uint_as_float(cur.x & 0xffff0000u);
                    xl[2] = __uint_as_float(cur.y << 16);
                    xl[3] = __uint_as_float(cur.y & 0xffff0000u);
                    float p = 0.f;
                    #pragma unroll
                    for (int j = 0; j < 4; j++) {
                        float v = xl[j] + xr[j];
                        v = fmaxf(v, 0.2f * v);
                        p = fmaf(v, at[j], p);
                    }
                    #pragma unroll
                    for (int off = 1; off < 64; off <<= 1) p += __shfl_xor(p, off, 64);
                    float wgt = __expf(p);           // no-max softmax
                    z += wgt;
                    #pragma unroll
                    for (int j = 0; j < 4; j++) acc[j] = fmaf(wgt, xl[j], acc[j]);
                }
                float inv = 1.f / z;
                #pragma unroll
                for (int j = 0; j < 4; j++) tot[j] = fmaf(acc[j], inv, tot[j]);
            }
        }
    }

    float v[4];
    float s1 = 0.f;
    #pragma unroll
    for (int j = 0; j < 4; j++) {
        int c = cl + j;
        float x = tot[j] + bias3[c] + bias3[256 + c] + bias3[512 + c];
        x = x > 0.f ? x : expm1f(x);
        v[j] = x;
        s1 += x;
    }
    #pragma unroll
    for (int off = 1; off < 64; off <<= 1) s1 += __shfl_xor(s1, off, 64);
    float mean = s1 * (1.f / DOUT);
    float s2 = 0.f;
    #pragma unroll
    for (int j = 0; j < 4; j++) { float d = v[j] - mean; s2 += d * d; }
    #pragma unroll
    for (int off = 1; off < 64; off <<= 1) s2 += __shfl_xor(s2, off, 64);
    float rstd = rsqrtf(s2 * (1.f / DOUT) + 1e-5f);
    f32x4 o;
    #pragma unroll
    for (int j = 0; j < 4; j++) {
        int c = cl + j;
        o[j] = (v[j] - mean) * rstd * gamma[c] + beta[c];
    }
    *(f32x4*)(out + (size_t)n * DOUT + cl) = o;
}

// ---------------------------------------------------------------------------
extern "C" void kernel_launch(void* const* d_in, const int* in_sizes, int n_in,
                              void* d_out, int out_size, void* d_ws, size_t ws_size,
                              hipStream_t stream) {
    const float* x       = (const float*)d_in[0];
    const int*   ei      = (const int*)d_in[1];
    const float* proj_w  = (const float*)d_in[2];
    const float* proj_b  = (const float*)d_in[3];
    const float* l01lw   = (const float*)d_in[4];
    const float* l01lb   = (const float*)d_in[5];
    const float* l01rw   = (const float*)d_in[6];
    const float* l01rb   = (const float*)d_in[7];
    const float* l01att  = (const float*)d_in[8];
    const float* l01bias = (const float*)d_in[9];
    const float* l2lw    = (const float*)d_in[10];
    const float* l2lb    = (const float*)d_in[11];
    const float* l2rw    = (const float*)d_in[12];
    const float* l2rb    = (const float*)d_in[13];
    const float* l2att   = (const float*)d_in[14];
    const float* l2bias  = (const float*)d_in[15];
    const float* g01     = (const float*)d_in[16];
    const float* b01     = (const float*)d_in[17];
    const float* g2      = (const float*)d_in[18];
    const float* b2      = (const float*)d_in[19];
    (void)in_sizes; (void)n_in; (void)out_size; (void)ws_size;

    // ---- workspace layout ----
    char* w = (char*)d_ws;
    size_t off = 0;
    auto carve = [&](size_t bytes) { void* p = w + off; off = (off + bytes + 255) & ~(size_t)255; return p; };
    unsigned short* h_b     = (unsigned short*)carve((size_t)NN * DH * 2);       // 20.5 MB
    unsigned short* xb      = (unsigned short*)carve((size_t)NN * DH * 2);       // 20.5 MB
    unsigned short* Cbuf    = (unsigned short*)carve((size_t)NN * 3072 * 2);     // 123 MB
    unsigned short* Wt      = (unsigned short*)carve((size_t)4194304 * 2);       // 8.4 MB
    int*            counts3 = (int*)           carve((size_t)3 * (NN + 1) * 4);
    int*            offs3   = (int*)           carve((size_t)3 * (NN + 1) * 4);
    int*            srcm    = (int*)           carve((size_t)3 * NE * 4);
    carve(65536);   // guard (also absorbs M-tail staging overreads)

    unsigned short* Wt_proj = Wt;                        // 512 x 512
    unsigned short* Wt_L0   = Wt_proj + 262144;          // 3072 x 512
    unsigned short* Wt_L1   = Wt_L0 + 3072 * 512;        // 3072 x 512
    unsigned short* Wt_L2   = Wt_L1 + 3072 * 512;        // 1536 x 512

    dim3 tb(256);
    const int MT  = (NN + 255) / 256;      // 79   (256-tile rows)
    const int MT1 = (NN + 127) / 128;      // 157  (128-tile rows)
    const int STRIPE1 = (MT1 + 7) / 8;     // 20

    // ---- convert x; transpose+cast all 19 weight matrices in ONE launch ----
    cvt_f2b_k<<<dim3(5000), tb, 0, stream>>>(x, xb, NN * DH);
    TTable tt;
    {
        int s = 0;
        tt.s[s++] = {proj_w, Wt_proj, 512};
        for (int li = 0; li < 2; li++) {
            unsigned short* base = li ? Wt_L1 : Wt_L0;
            for (int et = 0; et < 3; et++)
                tt.s[s++] = {l01lw + (size_t)(li * 3 + et) * 262144,
                             base + (size_t)et * 2 * 262144, 512};
            for (int et = 0; et < 3; et++)
                tt.s[s++] = {l01rw + (size_t)(li * 3 + et) * 262144,
                             base + 262144 + (size_t)et * 2 * 262144, 512};
        }
        for (int et = 0; et < 3; et++)
            tt.s[s++] = {l2lw + (size_t)et * 131072,
                         Wt_L2 + (size_t)et * 2 * 131072, 256};
        for (int et = 0; et < 3; et++)
            tt.s[s++] = {l2rw + (size_t)et * 131072,
                         Wt_L2 + 131072 + (size_t)et * 2 * 131072, 256};
    }
    transpose_all_k<<<dim3(256, 19), tb, 0, stream>>>(tt);

    // ---- merged CSR build ----
    hipMemsetAsync(counts3, 0, (size_t)3 * (NN + 1) * 4, stream);
    count_all_k<<<dim3((3 * NE + 255) / 256), tb, 0, stream>>>(ei, counts3);
    scan_par_k<<<dim3(3), dim3(1024), 0, stream>>>(counts3, offs3, NN);
    cursor_init_k<<<dim3((NN + 255) / 256), tb, 0, stream>>>(offs3, counts3);
    scatter_all_k<<<dim3((3 * NE + 255) / 256), tb, 0, stream>>>(ei, counts3, srcm);

    // ---- input projection + ELU -> h_b (128^2 kernel: good grid fill) ----
    gemm_k<1, 9><<<dim3(8 * STRIPE1 * 4), tb, 0, stream>>>(
        xb, Wt_proj, proj_b, proj_b, h_b, NN, 512, 512, MT1, 4, STRIPE1);

    // ---- layers 0, 1: merged GEMM (N=3072, free-running 256^2) + fused GAT --
    for (int li = 0; li < 2; li++) {
        gemm256_k<0, 9><<<dim3(MT * 12), dim3(512), 0, stream>>>(
            h_b, li ? Wt_L1 : Wt_L0,
            l01lb + (size_t)li * 3 * 512, l01rb + (size_t)li * 3 * 512,
            Cbuf, NN, 3072, 512, MT, 12);
        gat_fused01_k<<<dim3(NN / 4), tb, 0, stream>>>(
            Cbuf, offs3, srcm,
            l01att + (size_t)li * 3 * 512, l01bias + (size_t)li * 3 * 512,
            h_b, g01 + (size_t)li * DH, b01 + (size_t)li * DH, NN);
    }

    // ---- layer 2: merged GEMM (N=1536, 128^2: 4 blocks/CU) + fused GAT/LN ----
    gemm_k<0, 8><<<dim3(8 * STRIPE1 * 12), tb, 0, stream>>>(
        h_b, Wt_L2, l2lb, l2rb, Cbuf, NN, 1536, 512, MT1, 12, STRIPE1);
    gat_fused2_k<<<dim3(NN / 4), tb, 0, stream>>>(
        Cbuf, offs3, srcm, l2att, l2bias, g2, b2, (float*)d_out, NN);
}

// Round 11
// 613.607 us; speedup vs baseline: 1.1068x; 1.1068x over previous
//
#include <hip/hip_runtime.h>

// ---------------------------------------------------------------------------
// HeteroGATv2Encoder on MI355X (gfx950).
// fp32 in / fp32 out. R11 = exact reproduction of the session's best-measured
// configuration (R2, 642.5 us): 128^2 MFMA GEMMs everywhere (XCD swizzle, LDS
// XOR swizzle, LDS-staged coalesced epilogue); CSR edges + fused per-node GAT
// kernels (wave-per-(node,relation), dual-stream BRANCHLESS clamped prefetch,
// no-max softmax, transposed conflict-free LDS combine).
// Rationale: R3-R10 established that (a) gat kernels are occupancy-bound
// (VGPR>40 -> occ 45% -> regression: R5/R9/R10), (b) two independent GEMM
// schedules converge at ~90-96 us/dispatch, (c) totals favor this config.
// ---------------------------------------------------------------------------

#define NN 20000      // nodes
#define NE 100000     // edges per relation
#define DH 512        // hidden width (8 heads x 64)
#define DOUT 256

typedef __attribute__((ext_vector_type(8))) short short8;
typedef __attribute__((ext_vector_type(4))) short short4v;
typedef __attribute__((ext_vector_type(4))) float f32x4;

__device__ __forceinline__ float b2f(unsigned short s) {
    union { unsigned u; float f; } v; v.u = ((unsigned)s) << 16; return v.f;
}
__device__ __forceinline__ unsigned short f2b(float f) {
    unsigned u = __float_as_uint(f);
    u += 0x7FFFu + ((u >> 16) & 1u);   // RNE
    return (unsigned short)(u >> 16);
}
__device__ __forceinline__ void load_lds16(const unsigned short* g, unsigned short* l) {
    __builtin_amdgcn_global_load_lds(
        (const __attribute__((address_space(1))) unsigned int*)g,
        (__attribute__((address_space(3))) unsigned int*)l, 16, 0, 0);
}

// ---------------------------------------------------------------------------
__global__ void cvt_f2b_k(const float* __restrict__ in,
                          unsigned short* __restrict__ out, int n) {
    int i0 = (blockIdx.x * blockDim.x + threadIdx.x) * 8;
    if (i0 >= n) return;
    #pragma unroll
    for (int j = 0; j < 8; j++) out[i0 + j] = f2b(in[i0 + j]);
}

// ---------------------------------------------------------------------------
// Merged transpose+cast: 19 weight matrices in one launch.
// ---------------------------------------------------------------------------
struct TSeg { const float* in; unsigned short* out; int C; };
struct TTable { TSeg s[19]; };

__global__ void transpose_all_k(TTable t) {
    __shared__ float tile[32][33];
    TSeg d = t.s[blockIdx.y];
    int tiles_x = d.C >> 5;
    int nt = tiles_x << 4;               // tiles_x * 16
    if ((int)blockIdx.x >= nt) return;
    int bx = blockIdx.x % tiles_x, by = blockIdx.x / tiles_x;
    int c0 = bx * 32, r0 = by * 32;
    int tx = threadIdx.x & 31, ty = threadIdx.x >> 5;
    #pragma unroll
    for (int i = ty; i < 32; i += 8)
        tile[i][tx] = d.in[(size_t)(r0 + i) * d.C + c0 + tx];
    __syncthreads();
    #pragma unroll
    for (int i = ty; i < 32; i += 8)
        d.out[(size_t)(c0 + i) * 512 + r0 + tx] = f2b(tile[tx][i]);
}

// ---------------------------------------------------------------------------
// CSR build (merged over the 3 relations)
// ---------------------------------------------------------------------------
__global__ void count_all_k(const int* __restrict__ ei, int* __restrict__ counts) {
    int i = blockIdx.x * blockDim.x + threadIdx.x;
    if (i >= 3 * NE) return;
    int et = i / NE, idx = i - et * NE;
    int d = ei[(size_t)et * 2 * NE + NE + idx];
    atomicAdd(&counts[et * (NN + 1) + d], 1);
}

__global__ __launch_bounds__(1024)
void scan_par_k(const int* __restrict__ counts, int* __restrict__ offs, int n) {
    __shared__ int part[1024];
    const int* c = counts + (size_t)blockIdx.x * (n + 1);
    int* o = offs + (size_t)blockIdx.x * (n + 1);
    int tid = threadIdx.x;
    int per = (n + 1023) / 1024;
    int base = tid * per;
    int lim = min(base + per, n);
    int sum = 0;
    for (int i = base; i < lim; i++) sum += c[i];
    part[tid] = sum;
    __syncthreads();
    #pragma unroll
    for (int off = 1; off < 1024; off <<= 1) {
        int v = (tid >= off) ? part[tid - off] : 0;
        __syncthreads();
        part[tid] += v;
        __syncthreads();
    }
    int run = part[tid] - sum;
    for (int i = base; i < lim; i++) { o[i] = run; run += c[i]; }
    if (tid == 1023) o[n] = part[1023];
}

__global__ void scatter_all_k(const int* __restrict__ ei, int* __restrict__ cursor,
                              int* __restrict__ srcs_sorted) {
    int i = blockIdx.x * blockDim.x + threadIdx.x;
    if (i >= 3 * NE) return;
    int et = i / NE, idx = i - et * NE;
    int s = ei[(size_t)et * 2 * NE + idx];
    int d = ei[(size_t)et * 2 * NE + NE + idx];
    int p = atomicAdd(&cursor[et * (NN + 1) + d], 1);
    srcs_sorted[(size_t)et * NE + p] = s;
}

// ---------------------------------------------------------------------------
// Tiled GEMM: XCD swizzle + XOR-swizzled LDS + LDS-staged coalesced epilogue.
// ---------------------------------------------------------------------------
template<int ACT, int SEGL2>
__global__ __launch_bounds__(256)
void gemm_k(const unsigned short* __restrict__ A,
            const unsigned short* __restrict__ Bt,
            const float* __restrict__ lb,
            const float* __restrict__ rb,
            unsigned short* __restrict__ Cb,
            int M, int N, int K, int MT, int NT, int STRIPE) {
    __shared__ __align__(16) unsigned short smem[17408];   // 34.8 KB
    unsigned short* As = smem;           // 128*64
    unsigned short* Bs = smem + 8192;    // 128*64
    int bid = blockIdx.x;
    int xcd = bid & 7, r = bid >> 3;
    int mtile = xcd * STRIPE + r / NT;
    int ntile = r % NT;
    if (mtile >= MT) return;
    int bm0 = mtile * 128, bn0 = ntile * 128;

    int tid = threadIdx.x;
    int lane = tid & 63, wave = tid >> 6;
    int quad = lane >> 4, l16 = lane & 15;
    int rw = (wave >> 1) * 64, cw = (wave & 1) * 64;
    int rxor = l16 & 7;

    f32x4 acc[4][4];
    #pragma unroll
    for (int mi = 0; mi < 4; mi++)
        #pragma unroll
        for (int ni = 0; ni < 4; ni++) acc[mi][ni] = (f32x4){0.f, 0.f, 0.f, 0.f};

    for (int k0 = 0; k0 < K; k0 += 64) {
        #pragma unroll
        for (int i = 0; i < 4; i++) {
            int f = i * 256 + tid;
            int row = f >> 3, s = f & 7;
            int cg = s ^ (row & 7);
            load_lds16(A + (size_t)(bm0 + row) * K + k0 + cg * 8, As + f * 8);
        }
        #pragma unroll
        for (int i = 0; i < 4; i++) {
            int f = i * 256 + tid;
            int col = f >> 3, s = f & 7;
            int cg = s ^ (col & 7);
            load_lds16(Bt + (size_t)(bn0 + col) * K + k0 + cg * 8, Bs + f * 8);
        }
        __syncthreads();
        #pragma unroll
        for (int ki = 0; ki < 64; ki += 32) {
            int kch = quad + (ki >> 3);
            int slot = kch ^ rxor;
            short8 af[4], bf[4];
            #pragma unroll
            for (int mi = 0; mi < 4; mi++)
                af[mi] = *(const short8*)(As + (rw + mi * 16 + l16) * 64 + slot * 8);
            #pragma unroll
            for (int ni = 0; ni < 4; ni++)
                bf[ni] = *(const short8*)(Bs + (cw + ni * 16 + l16) * 64 + slot * 8);
            #pragma unroll
            for (int mi = 0; mi < 4; mi++)
                #pragma unroll
                for (int ni = 0; ni < 4; ni++)
                    acc[mi][ni] = __builtin_amdgcn_mfma_f32_16x16x32_bf16(
                        af[mi], bf[ni], acc[mi][ni], 0, 0, 0);
        }
        __syncthreads();
    }

    // ---- epilogue: bias(+ELU) -> bf16 tile in LDS (stride 136) ----
    #pragma unroll
    for (int ni = 0; ni < 4; ni++) {
        int col = cw + ni * 16 + l16;
        int seg = col >> (SEGL2 + 1);
        int lr = (col >> SEGL2) & 1;
        int cc2 = col & ((1 << SEGL2) - 1);
        float bv = (lr ? rb : lb)[(seg << SEGL2) + cc2];
        #pragma unroll
        for (int mi = 0; mi < 4; mi++) {
            int row = rw + mi * 16 + quad * 4;
            #pragma unroll
            for (int i = 0; i < 4; i++) {
                float v = acc[mi][ni][i] + bv;
                if (ACT == 1) v = v > 0.f ? v : expm1f(v);
                smem[(row + i) * 136 + col] = f2b(v);
            }
        }
    }
    __syncthreads();
    // ---- coalesced 16B stores ----
    #pragma unroll
    for (int it = 0; it < 8; it++) {
        int chunk = it * 256 + tid;
        int row = chunk >> 4, cc = chunk & 15;
        int grow = bm0 + row;
        if (grow < M) {
            uint4 d = *(const uint4*)(smem + row * 136 + cc * 8);
            *(uint4*)(Cb + (size_t)grow * N + bn0 + cc * 8) = d;
        }
    }
}

// ---------------------------------------------------------------------------
// Fused layer 0/1: one wave per (node, relation). Block 192 = 3 waves = 1 node.
// Dual-stream edge walk (front + back, depth-2 BRANCHLESS clamped prefetch).
// no-max softmax. Transposed conflict-free LDS combine; wave 0 finalizes.
// C layout [NN][3072] = et: XL(512)|XR(512).
// ---------------------------------------------------------------------------
__global__ __launch_bounds__(192)
void gat_fused01_k(const unsigned short* __restrict__ C,
                   const int* __restrict__ offs3,
                   const int* __restrict__ srcs3,
                   const float* __restrict__ att,     // [3][512]
                   const float* __restrict__ bias3,   // [3][512]
                   unsigned short* __restrict__ hb,   // in/out
                   const float* __restrict__ gamma,
                   const float* __restrict__ beta,
                   int n_nodes) {
    const unsigned LD = 3072;
    __shared__ float lds_tot[2 * DH];    // [et][j*64+lane] transposed layout
    int tid = threadIdx.x;
    int lane = tid & 63, et = tid >> 6;     // wave index == relation
    int n = blockIdx.x;
    int c0 = lane * 8;

    const int* offs = offs3 + et * (NN + 1);
    const int* srcs = srcs3 + (size_t)et * NE;
    int e0 = offs[n], e1 = offs[n + 1];

    float tot[8];
    #pragma unroll
    for (int j = 0; j < 8; j++) tot[j] = 0.f;

    if (e0 < e1) {
        const unsigned short* XL = C + et * 1024 + c0;
        float xr[8], at[8];
        {
            short8 t = *(const short8*)(C + (size_t)n * LD + et * 1024 + 512 + c0);
            #pragma unroll
            for (int j = 0; j < 8; j++) xr[j] = b2f((unsigned short)t[j]);
            #pragma unroll
            for (int j = 0; j < 8; j++) at[j] = att[et * 512 + c0 + j];
        }
        float z = 0.f;
        float acc[8];
        #pragma unroll
        for (int j = 0; j < 8; j++) acc[j] = 0.f;

        auto G = [&](int idx) {
            return *(const short8*)(XL + (unsigned)srcs[idx] * LD);
        };
        auto process = [&](short8 cur) {
            float xl[8];
            #pragma unroll
            for (int j = 0; j < 8; j++) xl[j] = b2f((unsigned short)cur[j]);
            float p = 0.f;
            #pragma unroll
            for (int j = 0; j < 8; j++) {
                float v = xl[j] + xr[j];
                v = fmaxf(v, 0.2f * v);          // leaky_relu 0.2 (slope<1)
                p = fmaf(v, at[j], p);
            }
            p += __shfl_xor(p, 1, 64);           // head = 8-lane group
            p += __shfl_xor(p, 2, 64);
            p += __shfl_xor(p, 4, 64);
            float wgt = __expf(p);               // no-max: |p| small, safe
            z += wgt;
            #pragma unroll
            for (int j = 0; j < 8; j++) acc[j] = fmaf(wgt, xl[j], acc[j]);
        };

        int ef = e0, eb = e1 - 1;
        short8 a0 = G(ef);
        short8 a1 = G(min(ef + 1, eb));
        short8 b0 = G(eb);
        short8 b1 = G(max(eb - 1, ef));
        while (ef < eb) {
            short8 ca = a0; a0 = a1; a1 = G(min(ef + 2, eb));
            short8 cb = b0; b0 = b1; b1 = G(max(eb - 2, ef));
            process(ca);
            process(cb);
            ef++; eb--;
        }
        if (ef == eb) process(a0);

        float inv = 1.f / z;
        #pragma unroll
        for (int j = 0; j < 8; j++) tot[j] = acc[j] * inv;
    }

    if (et) {
        float* dst = lds_tot + (et - 1) * DH + lane;
        #pragma unroll
        for (int j = 0; j < 8; j++) dst[j * 64] = tot[j];   // conflict-free
    }
    __syncthreads();
    if (et == 0) {
        // finalize: bias + ELU + residual + LN (single wave holds all 512 ch)
        unsigned short* hrow = hb + (size_t)n * DH + c0;
        short8 rt = *(const short8*)hrow;
        float v[8];
        float s1 = 0.f;
        #pragma unroll
        for (int j = 0; j < 8; j++) {
            int c = c0 + j;
            float x = tot[j] + lds_tot[j * 64 + lane] + lds_tot[DH + j * 64 + lane]
                    + bias3[c] + bias3[512 + c] + bias3[1024 + c];
            x = x > 0.f ? x : expm1f(x);
            x += b2f((unsigned short)rt[j]);
            v[j] = x;
            s1 += x;
        }
        #pragma unroll
        for (int off = 1; off < 64; off <<= 1) s1 += __shfl_xor(s1, off, 64);
        float mean = s1 * (1.f / DH);
        float s2 = 0.f;
        #pragma unroll
        for (int j = 0; j < 8; j++) { float d = v[j] - mean; s2 += d * d; }
        #pragma unroll
        for (int off = 1; off < 64; off <<= 1) s2 += __shfl_xor(s2, off, 64);
        float rstd = rsqrtf(s2 * (1.f / DH) + 1e-5f);
        short8 ov;
        #pragma unroll
        for (int j = 0; j < 8; j++) {
            int c = c0 + j;
            ov[j] = (short)f2b((v[j] - mean) * rstd * gamma[c] + beta[c]);
        }
        *(short8*)hrow = ov;
    }
    (void)n_nodes;
}

// ---------------------------------------------------------------------------
// Fused layer 2: one wave per (node, relation). Block 192 = 3 waves = 1 node.
// Dual-stream edge walk (branchless clamped prefetch), no-max softmax,
// transposed LDS combine; wave 0 finalizes (bias+ELU+LN) -> f32 out.
// C layout [NN][1536] = et: XL(256)|XR(256).
// ---------------------------------------------------------------------------
__global__ __launch_bounds__(192)
void gat_fused2_k(const unsigned short* __restrict__ C,
                  const int* __restrict__ offs3,
                  const int* __restrict__ srcs3,
                  const float* __restrict__ att,     // [3][256]
                  const float* __restrict__ bias3,   // [3][256]
                  const float* __restrict__ gamma,
                  const float* __restrict__ beta,
                  float* __restrict__ out, int n_nodes) {
    const unsigned LD = 1536;
    __shared__ float lds_tot[2 * DOUT];  // transposed layout
    int tid = threadIdx.x;
    int lane = tid & 63, et = tid >> 6;
    int n = blockIdx.x;
    int c0 = lane * 4;

    const int* offs = offs3 + et * (NN + 1);
    const int* srcs = srcs3 + (size_t)et * NE;
    int e0 = offs[n], e1 = offs[n + 1];

    float tot[4] = {0.f, 0.f, 0.f, 0.f};

    if (e0 < e1) {
        const unsigned short* XL = C + et * 512 + c0;
        float xr[4], at[4];
        {
            short4v t = *(const short4v*)(C + (size_t)n * LD + et * 512 + 256 + c0);
            #pragma unroll
            for (int j = 0; j < 4; j++) xr[j] = b2f((unsigned short)t[j]);
            #pragma unroll
            for (int j = 0; j < 4; j++) at[j] = att[et * 256 + c0 + j];
        }
        float z = 0.f;
        float acc[4] = {0.f, 0.f, 0.f, 0.f};

        auto G = [&](int idx) {
            return *(const short4v*)(XL + (unsigned)srcs[idx] * LD);
        };
        auto process = [&](short4v cur) {
            float xl[4];
            #pragma unroll
            for (int j = 0; j < 4; j++) xl[j] = b2f((unsigned short)cur[j]);
            float p = 0.f;
            #pragma unroll
            for (int j = 0; j < 4; j++) {
                float v = xl[j] + xr[j];
                v = fmaxf(v, 0.2f * v);
                p = fmaf(v, at[j], p);
            }
            #pragma unroll
            for (int off = 1; off < 64; off <<= 1) p += __shfl_xor(p, off, 64);
            float wgt = __expf(p);               // no-max softmax
            z += wgt;
            #pragma unroll
            for (int j = 0; j < 4; j++) acc[j] = fmaf(wgt, xl[j], acc[j]);
        };

        int ef = e0, eb = e1 - 1;
        short4v a0 = G(ef);
        short4v a1 = G(min(ef + 1, eb));
        short4v b0 = G(eb);
        short4v b1 = G(max(eb - 1, ef));
        while (ef < eb) {
            short4v ca = a0; a0 = a1; a1 = G(min(ef + 2, eb));
            short4v cb = b0; b0 = b1; b1 = G(max(eb - 2, ef));
            process(ca);
            process(cb);
            ef++; eb--;
        }
        if (ef == eb) process(a0);

        float inv = 1.f / z;
        #pragma unroll
        for (int j = 0; j < 4; j++) tot[j] = acc[j] * inv;
    }

    if (et) {
        float* dst = lds_tot + (et - 1) * DOUT + lane;
        #pragma unroll
        for (int j = 0; j < 4; j++) dst[j * 64] = tot[j];   // conflict-free
    }
    __syncthreads();
    if (et == 0) {
        float v[4];
        float s1 = 0.f;
        #pragma unroll
        for (int j = 0; j < 4; j++) {
            int c = c0 + j;
            float x = tot[j] + lds_tot[j * 64 + lane] + lds_tot[DOUT + j * 64 + lane]
                    + bias3[c] + bias3[256 + c] + bias3[512 + c];
            x = x > 0.f ? x : expm1f(x);
            v[j] = x;
            s1 += x;
        }
        #pragma unroll
        for (int off = 1; off < 64; off <<= 1) s1 += __shfl_xor(s1, off, 64);
        float mean = s1 * (1.f / DOUT);
        float s2 = 0.f;
        #pragma unroll
        for (int j = 0; j < 4; j++) { float d = v[j] - mean; s2 += d * d; }
        #pragma unroll
        for (int off = 1; off < 64; off <<= 1) s2 += __shfl_xor(s2, off, 64);
        float rstd = rsqrtf(s2 * (1.f / DOUT) + 1e-5f);
        f32x4 o;
        #pragma unroll
        for (int j = 0; j < 4; j++) {
            int c = c0 + j;
            o[j] = (v[j] - mean) * rstd * gamma[c] + beta[c];
        }
        *(f32x4*)(out + (size_t)n * DOUT + c0) = o;
    }
    (void)n_nodes;
}

// ---------------------------------------------------------------------------
extern "C" void kernel_launch(void* const* d_in, const int* in_sizes, int n_in,
                              void* d_out, int out_size, void* d_ws, size_t ws_size,
                              hipStream_t stream) {
    const float* x       = (const float*)d_in[0];
    const int*   ei      = (const int*)d_in[1];
    const float* proj_w  = (const float*)d_in[2];
    const float* proj_b  = (const float*)d_in[3];
    const float* l01lw   = (const float*)d_in[4];
    const float* l01lb   = (const float*)d_in[5];
    const float* l01rw   = (const float*)d_in[6];
    const float* l01rb   = (const float*)d_in[7];
    const float* l01att  = (const float*)d_in[8];
    const float* l01bias = (const float*)d_in[9];
    const float* l2lw    = (const float*)d_in[10];
    const float* l2lb    = (const float*)d_in[11];
    const float* l2rw    = (const float*)d_in[12];
    const float* l2rb    = (const float*)d_in[13];
    const float* l2att   = (const float*)d_in[14];
    const float* l2bias  = (const float*)d_in[15];
    const float* g01     = (const float*)d_in[16];
    const float* b01     = (const float*)d_in[17];
    const float* g2      = (const float*)d_in[18];
    const float* b2      = (const float*)d_in[19];
    (void)in_sizes; (void)n_in; (void)out_size; (void)ws_size;

    // ---- workspace layout ----
    char* w = (char*)d_ws;
    size_t off = 0;
    auto carve = [&](size_t bytes) { void* p = w + off; off = (off + bytes + 255) & ~(size_t)255; return p; };
    unsigned short* h_b     = (unsigned short*)carve((size_t)NN * DH * 2);       // 20.5 MB
    unsigned short* xb      = (unsigned short*)carve((size_t)NN * DH * 2);       // 20.5 MB
    unsigned short* Cbuf    = (unsigned short*)carve((size_t)NN * 3072 * 2);     // 123 MB
    unsigned short* Wt      = (unsigned short*)carve((size_t)4194304 * 2);       // 8.4 MB
    int*            counts3 = (int*)           carve((size_t)3 * (NN + 1) * 4);
    int*            offs3   = (int*)           carve((size_t)3 * (NN + 1) * 4);
    int*            srcs3   = (int*)           carve((size_t)3 * NE * 4);
    carve(65536);   // guard

    unsigned short* Wt_proj = Wt;                        // 512 x 512
    unsigned short* Wt_L0   = Wt_proj + 262144;          // 3072 x 512
    unsigned short* Wt_L1   = Wt_L0 + 3072 * 512;        // 3072 x 512
    unsigned short* Wt_L2   = Wt_L1 + 3072 * 512;        // 1536 x 512

    dim3 tb(256);
    const int MT1 = (NN + 127) / 128;      // 157  (128-tile rows)
    const int STRIPE1 = (MT1 + 7) / 8;     // 20

    // ---- convert x; transpose+cast all 19 weight matrices in ONE launch ----
    cvt_f2b_k<<<dim3(5000), tb, 0, stream>>>(x, xb, NN * DH);
    TTable tt;
    {
        int s = 0;
        tt.s[s++] = {proj_w, Wt_proj, 512};
        for (int li = 0; li < 2; li++) {
            unsigned short* base = li ? Wt_L1 : Wt_L0;
            for (int et = 0; et < 3; et++)
                tt.s[s++] = {l01lw + (size_t)(li * 3 + et) * 262144,
                             base + (size_t)et * 2 * 262144, 512};
            for (int et = 0; et < 3; et++)
                tt.s[s++] = {l01rw + (size_t)(li * 3 + et) * 262144,
                             base + 262144 + (size_t)et * 2 * 262144, 512};
        }
        for (int et = 0; et < 3; et++)
            tt.s[s++] = {l2lw + (size_t)et * 131072,
                         Wt_L2 + (size_t)et * 2 * 131072, 256};
        for (int et = 0; et < 3; et++)
            tt.s[s++] = {l2rw + (size_t)et * 131072,
                         Wt_L2 + 131072 + (size_t)et * 2 * 131072, 256};
    }
    transpose_all_k<<<dim3(256, 19), tb, 0, stream>>>(tt);

    // ---- CSR build (merged) ----
    hipMemsetAsync(counts3, 0, (size_t)3 * (NN + 1) * 4, stream);
    count_all_k<<<dim3((3 * NE + 255) / 256), tb, 0, stream>>>(ei, counts3);
    scan_par_k<<<dim3(3), dim3(1024), 0, stream>>>(counts3, offs3, NN);
    hipMemcpyAsync(counts3, offs3, (size_t)3 * (NN + 1) * 4,
                   hipMemcpyDeviceToDevice, stream);
    scatter_all_k<<<dim3((3 * NE + 255) / 256), tb, 0, stream>>>(ei, counts3, srcs3);

    // ---- input projection + ELU -> h_b ----
    gemm_k<1, 9><<<dim3(8 * STRIPE1 * 4), tb, 0, stream>>>(
        xb, Wt_proj, proj_b, proj_b, h_b, NN, 512, 512, MT1, 4, STRIPE1);

    // ---- layers 0, 1: merged GEMM (N=3072) + fused GAT/finalize ----
    for (int li = 0; li < 2; li++) {
        gemm_k<0, 9><<<dim3(8 * STRIPE1 * 24), tb, 0, stream>>>(
            h_b, li ? Wt_L1 : Wt_L0,
            l01lb + (size_t)li * 3 * 512, l01rb + (size_t)li * 3 * 512,
            Cbuf, NN, 3072, 512, MT1, 24, STRIPE1);
        gat_fused01_k<<<dim3(NN), dim3(192), 0, stream>>>(
            Cbuf, offs3, srcs3,
            l01att + (size_t)li * 3 * 512, l01bias + (size_t)li * 3 * 512,
            h_b, g01 + (size_t)li * DH, b01 + (size_t)li * DH, NN);
    }

    // ---- layer 2: merged GEMM (N=1536) + fused GAT/LN -> d_out ----
    gemm_k<0, 8><<<dim3(8 * STRIPE1 * 12), tb, 0, stream>>>(
        h_b, Wt_L2, l2lb, l2rb, Cbuf, NN, 1536, 512, MT1, 12, STRIPE1);
    gat_fused2_k<<<dim3(NN), dim3(192), 0, stream>>>(
        Cbuf, offs3, srcs3, l2att, l2bias, g2, b2, (float*)d_out, NN);
}